// Round 9
// baseline (729.884 us; speedup 1.0000x reference)
//
#include <hip/hip_runtime.h>

#define NUM_USERS 50000
#define NUM_ITEMS 50000
#define NUM_CATS  500
#define D         64
#define N_LAYERS  3
#define N_EDGES   500000
#define NNZ_G     1000000
#define NNZ_GX    2000000
#define BATCH     8192
#define N_NODES   (NUM_USERS + NUM_ITEMS)

// G-path fine buckets
#define BKT_SHIFT 4
#define BKT_W     16
#define NBKT      (N_NODES / BKT_W)   // 6250

// C-path super-buckets
#define SB_SHIFT  9
#define SB_W      512
#define NSB       ((N_NODES + SB_W - 1) / SB_W)   // 196
#define P1_K      8
#define P1_TILE   (256 * P1_K)        // 2048 nnz per WG
#define P2_BINS   (SB_W * 8)          // 4096: (dst_local<<3)|src_octant

__device__ __forceinline__ unsigned bf16rne(float f) {
    unsigned u = __float_as_uint(f);
    return (u + 0x7FFFu + ((u >> 16) & 1u)) >> 16;
}
__device__ __forceinline__ void bf16x8_to_f8(uint4 w, float* r) {
    r[0] = __uint_as_float(w.x << 16); r[1] = __uint_as_float(w.x & 0xFFFF0000u);
    r[2] = __uint_as_float(w.y << 16); r[3] = __uint_as_float(w.y & 0xFFFF0000u);
    r[4] = __uint_as_float(w.z << 16); r[5] = __uint_as_float(w.z & 0xFFFF0000u);
    r[6] = __uint_as_float(w.w << 16); r[7] = __uint_as_float(w.w & 0xFFFF0000u);
}
__device__ __forceinline__ uint4 f8_to_bf16x8(const float* r) {
    uint4 w;
    w.x = bf16rne(r[0]) | (bf16rne(r[1]) << 16);
    w.y = bf16rne(r[2]) | (bf16rne(r[3]) << 16);
    w.z = bf16rne(r[4]) | (bf16rne(r[5]) << 16);
    w.w = bf16rne(r[6]) | (bf16rne(r[7]) << 16);
    return w;
}

// ---------- degree ----------
__global__ void deg_kernel(const int* __restrict__ tu, const int* __restrict__ ti,
                           float* __restrict__ deg) {
    int e = blockIdx.x * blockDim.x + threadIdx.x;
    if (e >= N_EDGES) return;
    unsafeAtomicAdd(deg + tu[e], 1.0f);
    unsafeAtomicAdd(deg + NUM_USERS + ti[e], 1.0f);
}

__global__ void dinv_kernel(float* __restrict__ deg) {
    int n = blockIdx.x * blockDim.x + threadIdx.x;
    if (n < N_NODES) deg[n] = 1.0f / (deg[n] + 1e-9f);
}

// ---------- init x (bf16 only) ----------
__global__ void init_x_kernel(const float* __restrict__ ue, const float* __restrict__ ie,
                              ushort* __restrict__ xb) {
    int i4 = blockIdx.x * blockDim.x + threadIdx.x;
    if (i4 >= N_NODES * D / 4) return;
    const int half = NUM_USERS * D / 4;
    float4 v = (i4 < half) ? ((const float4*)ue)[i4] : ((const float4*)ie)[i4 - half];
    uint2 p;
    p.x = bf16rne(v.x) | (bf16rne(v.y) << 16);
    p.y = bf16rne(v.z) | (bf16rne(v.w) << 16);
    ((uint2*)xb)[i4] = p;
}

// ---------- C: super-bucket histogram ----------
__global__ void histsb_c_kernel(const int* __restrict__ gx_rows,
                                const int* __restrict__ tu, const int* __restrict__ ti,
                                int* __restrict__ cnt) {
    __shared__ int h[NSB];
    for (int i = threadIdx.x; i < NSB; i += blockDim.x) h[i] = 0;
    __syncthreads();
    int stride = gridDim.x * blockDim.x;
    for (int j = blockIdx.x * blockDim.x + threadIdx.x; j < NNZ_GX; j += stride) {
        int r = gx_rows[j];
        atomicAdd(h + (tu[r] >> SB_SHIFT), 1);
        atomicAdd(h + ((NUM_USERS + ti[r]) >> SB_SHIFT), 1);
    }
    __syncthreads();
    for (int i = threadIdx.x; i < NSB; i += blockDim.x)
        if (h[i]) atomicAdd(cnt + i, h[i]);
}

// ---------- C: tiny scan ----------
__global__ void scansb_kernel(const int* __restrict__ cnt, int* __restrict__ off,
                              int* __restrict__ cur, int* __restrict__ row_sentinel) {
    if (threadIdx.x == 0) {
        int run = 0;
        for (int i = 0; i < NSB; ++i) { off[i] = run; cur[i] = run; run += cnt[i]; }
        off[NSB] = run;
        row_sentinel[0] = run;
    }
}

// ---------- C phase 1: WG multisplit append (SoA recs) ----------
__global__ void __launch_bounds__(256) p1c_kernel(
        const int* __restrict__ gx_rows, const int* __restrict__ gx_cols,
        const float* __restrict__ gx_vals,
        const int* __restrict__ tu, const int* __restrict__ ti,
        const int* __restrict__ i2c,
        int* __restrict__ sbcur, int2* __restrict__ out) {
    __shared__ int2 recs[2 * P1_TILE];            // 32 KB
    __shared__ int h[NSB], base[NSB], cur[NSB];
    int t = threadIdx.x;
    for (int i = t; i < NSB; i += 256) { h[i] = 0; cur[i] = 0; }
    __syncthreads();
    int tb = blockIdx.x * P1_TILE;
    #pragma unroll
    for (int k = 0; k < P1_K; ++k) {
        int l = t + k * 256;
        int j = tb + l;
        if (j < NNZ_GX) {
            int r = gx_rows[j], c = gx_cols[j];
            unsigned vb = bf16rne(gx_vals[j]);
            int tur = tu[r], tir = ti[r], tuc = tu[c], tic = ti[c];
            int cat = i2c[tic];
            int ylo = (int)(vb << 16) | (cat << 1);
            unsigned dstu = (unsigned)tur;           int srcu = tuc;
            unsigned dsti = (unsigned)(NUM_USERS + tir); int srci = NUM_USERS + tic;
            recs[l] = make_int2((int)((dstu << 15) | (unsigned)(srcu & 0x7FFF)),
                                ylo | (((srcu >> 15) & 3) << 10));
            recs[P1_TILE + l] = make_int2((int)((dsti << 15) | (unsigned)(srci & 0x7FFF)),
                                          ylo | (((srci >> 15) & 3) << 10) | 1);
            atomicAdd(h + (int)(dstu >> SB_SHIFT), 1);
            atomicAdd(h + (int)(dsti >> SB_SHIFT), 1);
        }
    }
    __syncthreads();
    if (t < NSB) base[t] = atomicAdd(sbcur + t, h[t]);
    __syncthreads();
    int rem = NNZ_GX - tb;
    int nv = rem < P1_TILE ? rem : P1_TILE;
    for (int s = t; s < nv; s += 256) {
        int2 rec = recs[s];
        int bkt = (int)(((unsigned)rec.x) >> 24);
        int p = base[bkt] + atomicAdd(cur + bkt, 1);
        out[p] = rec;
        rec = recs[P1_TILE + s];
        bkt = (int)(((unsigned)rec.x) >> 24);
        p = base[bkt] + atomicAdd(cur + bkt, 1);
        out[p] = rec;
    }
}

// ---------- C phase 2: sort by (dst_local, src_octant), emits rowC ----------
__global__ void __launch_bounds__(512) p2c_kernel(
        const int* __restrict__ sboff, const int2* __restrict__ raw,
        int2* __restrict__ sorted, int* __restrict__ rowC) {
    int b = blockIdx.x;
    int beg = sboff[b], end = sboff[b + 1];
    __shared__ int h[P2_BINS];     // 16 KB
    __shared__ int cur[P2_BINS];   // 16 KB
    __shared__ int tsum[512];
    int t = threadIdx.x;
    #pragma unroll
    for (int k = 0; k < 8; ++k) h[t + k * 512] = 0;
    __syncthreads();
    for (int i = beg + t; i < end; i += 512) {
        int2 e = raw[i];
        unsigned rx = (unsigned)e.x;
        int dl = (int)((rx >> 15) & (SB_W - 1));
        int src = (int)(rx & 0x7FFF) | (((e.y >> 10) & 3) << 15);
        atomicAdd(h + ((dl << 3) | (src >> 14)), 1);
    }
    __syncthreads();
    // two-level exclusive scan: thread t owns bins [8t, 8t+8)
    int local[8];
    int s = 0;
    #pragma unroll
    for (int k = 0; k < 8; ++k) { local[k] = s; s += h[8 * t + k]; }
    tsum[t] = s;
    __syncthreads();
    for (int o = 1; o < 512; o <<= 1) {
        int v = (t >= o) ? tsum[t - o] : 0;
        __syncthreads();
        tsum[t] += v;
        __syncthreads();
    }
    int base0 = beg + tsum[t] - s;   // exclusive prefix of this thread's bins
    #pragma unroll
    for (int k = 0; k < 8; ++k) cur[8 * t + k] = base0 + local[k];
    __syncthreads();
    int rstart = cur[t << 3];        // start of node t's first octant bin
    int node = b * SB_W + t;
    if (node < N_NODES) rowC[node] = rstart;
    __syncthreads();
    for (int i = beg + t; i < end; i += 512) {
        int2 e = raw[i];
        unsigned rx = (unsigned)e.x;
        int dl = (int)((rx >> 15) & (SB_W - 1));
        int src = (int)(rx & 0x7FFF) | (((e.y >> 10) & 3) << 15);
        int p = atomicAdd(cur + ((dl << 3) | (src >> 14)), 1);
        sorted[p] = make_int2((src << 10) | (e.y & 0x3FF), e.y & 0xFFFF0000);
    }
}

// ---------- G path ----------
__global__ void histg_kernel(const int* __restrict__ g_rows, int* __restrict__ cnt) {
    __shared__ int h[NBKT];
    for (int i = threadIdx.x; i < NBKT; i += blockDim.x) h[i] = 0;
    __syncthreads();
    int stride = gridDim.x * blockDim.x;
    for (int e = blockIdx.x * blockDim.x + threadIdx.x; e < NNZ_G; e += stride)
        atomicAdd(h + (g_rows[e] >> BKT_SHIFT), 1);
    __syncthreads();
    for (int i = threadIdx.x; i < NBKT; i += blockDim.x)
        if (h[i]) atomicAdd(cnt + i, h[i]);
}

__global__ void scang_kernel(const int* __restrict__ cnt, int* __restrict__ off,
                             int* __restrict__ cur, int* __restrict__ row) {
    __shared__ int sums[1024];
    const int T = 1024;
    const int strip = (NBKT + T - 1) / T;
    int t = threadIdx.x;
    int beg = t * strip;
    int end = beg + strip; if (end > NBKT) end = NBKT;
    int s = 0;
    for (int i = beg; i < end; ++i) s += cnt[i];
    sums[t] = s;
    __syncthreads();
    if (t == 0) {
        int run = 0;
        for (int i = 0; i < T; ++i) { int v = sums[i]; sums[i] = run; run += v; }
        off[NBKT] = run;
        row[N_NODES] = run;
    }
    __syncthreads();
    int run = sums[t];
    for (int i = beg; i < end; ++i) { off[i] = run; cur[i] = run; run += cnt[i]; }
}

__global__ void append_g_kernel(const int* __restrict__ g_rows, const int* __restrict__ g_cols,
                                const float* __restrict__ g_vals,
                                int* __restrict__ cur, int2* __restrict__ edges) {
    int e = blockIdx.x * blockDim.x + threadIdx.x;
    if (e >= NNZ_G) return;
    int dst = g_rows[e];
    int p = atomicAdd(cur + (dst >> BKT_SHIFT), 1);
    edges[p] = make_int2(((dst & (BKT_W - 1)) << 17) | g_cols[e], __float_as_int(g_vals[e]));
}

// sort by (dst_local, src_octant): 128 bins
__global__ void sort_g_kernel(const int* __restrict__ off, const int2* __restrict__ raw,
                              int2* __restrict__ sorted, int* __restrict__ rowG) {
    int b = blockIdx.x;
    int base = off[b], end = off[b + 1];
    __shared__ int h[128], cur[128], scn[128];
    for (int i = threadIdx.x; i < 128; i += blockDim.x) h[i] = 0;
    __syncthreads();
    for (int i = base + threadIdx.x; i < end; i += blockDim.x) {
        int ex = raw[i].x;
        int dl = (ex >> 17) & 15;
        int src = ex & 0x1FFFF;
        atomicAdd(h + ((dl << 3) | (src >> 14)), 1);
    }
    __syncthreads();
    if (threadIdx.x == 0) {
        int run = 0;
        for (int k = 0; k < 128; ++k) { scn[k] = run; cur[k] = run; run += h[k]; }
    }
    __syncthreads();
    if (threadIdx.x < BKT_W) rowG[b * BKT_W + threadIdx.x] = base + scn[threadIdx.x << 3];
    for (int i = base + threadIdx.x; i < end; i += blockDim.x) {
        int2 e = raw[i];
        int dl = (e.x >> 17) & 15;
        int src = e.x & 0x1FFFF;
        int p = base + atomicAdd(cur + ((dl << 3) | (src >> 14)), 1);
        sorted[p] = make_int2(src << 6, e.y);  // src*64 element index
    }
}

// ---------- pull SpMM (G): one 32-lane half-wave per node, 8 lanes/edge ----------
__global__ void pull_g_kernel(const int* __restrict__ row, const int2* __restrict__ edges,
                              const ushort* __restrict__ xb, ushort* __restrict__ tb) {
    int node = (blockIdx.x * blockDim.x + threadIdx.x) >> 5;
    int l32 = threadIdx.x & 31;
    if (node >= N_NODES) return;
    int g = l32 >> 3;
    int s = l32 & 7;
    int beg = row[node], end = row[node + 1];
    float acc[8] = {0.f, 0.f, 0.f, 0.f, 0.f, 0.f, 0.f, 0.f};
    #pragma unroll 2
    for (int i = beg + g; i < end; i += 4) {
        int2 e = edges[i];
        float v = __int_as_float(e.y);
        uint4 w = *(const uint4*)(xb + e.x + s * 8);
        float xv[8];
        bf16x8_to_f8(w, xv);
        #pragma unroll
        for (int d = 0; d < 8; ++d) acc[d] += v * xv[d];
    }
    #pragma unroll
    for (int d = 0; d < 8; ++d) {
        acc[d] += __shfl_xor(acc[d], 8, 64);
        acc[d] += __shfl_xor(acc[d], 16, 64);
    }
    if (l32 < 8) {
        uint4 p = f8_to_bf16x8(acc);
        *(uint4*)(tb + (size_t)node * D + s * 8) = p;
    }
}

// ---------- pull SpMM (C) fused with finalize: half-wave per node ----------
template <int LAYER0>
__global__ void pull_c_fused(const int* __restrict__ row, const int2* __restrict__ edges,
                             const float* __restrict__ catbase,
                             const ushort* __restrict__ tb,
                             const float* __restrict__ dinv,
                             ushort* __restrict__ xb, float* __restrict__ accb) {
    int node = (blockIdx.x * blockDim.x + threadIdx.x) >> 5;
    int l32 = threadIdx.x & 31;
    if (node >= N_NODES) return;
    int g = l32 >> 3;
    int s = l32 & 7;
    int beg = row[node], end = row[node + 1];
    float acc[8] = {0.f, 0.f, 0.f, 0.f, 0.f, 0.f, 0.f, 0.f};
    #pragma unroll 2
    for (int i = beg + g; i < end; i += 4) {
        int2 e = edges[i];
        float v = __int_as_float(e.y);
        int src = e.x >> 10;
        uint4 w = *(const uint4*)(tb + (size_t)src * D + s * 8);
        float xv[8];
        bf16x8_to_f8(w, xv);
        if (LAYER0) {
            int code = e.x & 1023;
            const float* cb = catbase + (code >> 1) * (2 * D) + ((code & 1) << 6) + s * 8;
            float4 c0 = *(const float4*)cb;
            float4 c1 = *(const float4*)(cb + 4);
            xv[0] += c0.x; xv[1] += c0.y; xv[2] += c0.z; xv[3] += c0.w;
            xv[4] += c1.x; xv[5] += c1.y; xv[6] += c1.z; xv[7] += c1.w;
        }
        #pragma unroll
        for (int d = 0; d < 8; ++d) acc[d] += v * xv[d];
    }
    #pragma unroll
    for (int d = 0; d < 8; ++d) {
        acc[d] += __shfl_xor(acc[d], 8, 64);
        acc[d] += __shfl_xor(acc[d], 16, 64);
    }
    if (l32 < 8) {
        float di = dinv[node];
        size_t o = (size_t)node * D + s * 8;
        uint4 tw = *(const uint4*)(tb + o);
        float tv[8];
        bf16x8_to_f8(tw, tv);
        float nx[8];
        #pragma unroll
        for (int d = 0; d < 8; ++d) nx[d] = (acc[d] * di + tv[d]) * 0.5f;
        *(uint4*)(xb + o) = f8_to_bf16x8(nx);
        float4 a0 = *(const float4*)(accb + o);
        float4 a1 = *(const float4*)(accb + o + 4);
        a0.x += nx[0]; a0.y += nx[1]; a0.z += nx[2]; a0.w += nx[3];
        a1.x += nx[4]; a1.y += nx[5]; a1.z += nx[6]; a1.w += nx[7];
        *(float4*)(accb + o) = a0;
        *(float4*)(accb + o + 4) = a1;
    }
}

// ---------- gamma ----------
__global__ void gamma_kernel(const int* __restrict__ users, const int* __restrict__ items,
                             const float* __restrict__ acc, float* __restrict__ out) {
    int wave = (blockIdx.x * blockDim.x + threadIdx.x) >> 6;
    int lane = threadIdx.x & 63;
    if (wave >= BATCH) return;
    int u = users[wave], it = items[wave];
    float p = acc[(size_t)u * D + lane] * acc[(size_t)(NUM_USERS + it) * D + lane];
#pragma unroll
    for (int off = 32; off > 0; off >>= 1) p += __shfl_down(p, off, 64);
    if (lane == 0) out[wave] = p * (1.0f / 9.0f);
}

extern "C" void kernel_launch(void* const* d_in, const int* in_sizes, int n_in,
                              void* d_out, int out_size, void* d_ws, size_t ws_size,
                              hipStream_t stream) {
    const float* user_emb = (const float*)d_in[0];
    const float* item_emb = (const float*)d_in[1];
    const float* cat_emb  = (const float*)d_in[2];
    const float* g_vals   = (const float*)d_in[3];
    const float* gx_vals  = (const float*)d_in[4];
    const int* g_rows  = (const int*)d_in[5];
    const int* g_cols  = (const int*)d_in[6];
    const int* gx_rows = (const int*)d_in[7];
    const int* gx_cols = (const int*)d_in[8];
    const int* train_users = (const int*)d_in[9];
    const int* train_items = (const int*)d_in[10];
    const int* i2c   = (const int*)d_in[11];
    const int* users = (const int*)d_in[12];
    const int* items = (const int*)d_in[13];
    float* out = (float*)d_out;

    char* ws = (char*)d_ws;
    size_t off = 0;
    auto alloc = [&](size_t bytes) -> void* {
        void* p = ws + off;
        off += (bytes + 255) & ~(size_t)255;
        return p;
    };
    const size_t NB = (size_t)N_NODES * D * sizeof(float);
    const size_t NBH = (size_t)N_NODES * D * sizeof(ushort);
    ushort* xb   = (ushort*)alloc(NBH);
    ushort* tb   = (ushort*)alloc(NBH);
    float*  accb = (float*)alloc(NB);
    float*  dinv = (float*)alloc((size_t)N_NODES * sizeof(float));
    int*  sbhC  = (int*)alloc((size_t)NSB * sizeof(int));
    int*  sboffC= (int*)alloc((size_t)(NSB + 1) * sizeof(int));
    int*  sbcurC= (int*)alloc((size_t)NSB * sizeof(int));
    int*  cntG  = (int*)alloc((size_t)NBKT * sizeof(int));
    int*  offG  = (int*)alloc((size_t)(NBKT + 1) * sizeof(int));
    int*  curG  = (int*)alloc((size_t)NBKT * sizeof(int));
    int*  rowC  = (int*)alloc((size_t)(N_NODES + 1) * sizeof(int));
    int*  rowG  = (int*)alloc((size_t)(N_NODES + 1) * sizeof(int));
    int2* edgeCr = (int2*)alloc((size_t)2 * NNZ_GX * sizeof(int2));
    int2* edgeCs = (int2*)alloc((size_t)2 * NNZ_GX * sizeof(int2));
    int2* edgeGr = (int2*)alloc((size_t)NNZ_G * sizeof(int2));
    int2* edgeGs = (int2*)alloc((size_t)NNZ_G * sizeof(int2));

    hipMemsetAsync(accb, 0, NB, stream);
    hipMemsetAsync(dinv, 0, (size_t)N_NODES * sizeof(float), stream);
    hipMemsetAsync(sbhC, 0, (size_t)NSB * sizeof(int), stream);
    hipMemsetAsync(cntG, 0, (size_t)NBKT * sizeof(int), stream);

    init_x_kernel<<<(N_NODES * D / 4 + 255) / 256, 256, 0, stream>>>(user_emb, item_emb, xb);
    deg_kernel<<<(N_EDGES + 255) / 256, 256, 0, stream>>>(train_users, train_items, dinv);
    dinv_kernel<<<(N_NODES + 255) / 256, 256, 0, stream>>>(dinv);

    // C build
    histsb_c_kernel<<<256, 256, 0, stream>>>(gx_rows, train_users, train_items, sbhC);
    scansb_kernel<<<1, 64, 0, stream>>>(sbhC, sboffC, sbcurC, rowC + N_NODES);
    p1c_kernel<<<(NNZ_GX + P1_TILE - 1) / P1_TILE, 256, 0, stream>>>(
        gx_rows, gx_cols, gx_vals, train_users, train_items, i2c, sbcurC, edgeCr);
    p2c_kernel<<<NSB, 512, 0, stream>>>(sboffC, edgeCr, edgeCs, rowC);

    // G build
    histg_kernel<<<256, 256, 0, stream>>>(g_rows, cntG);
    scang_kernel<<<1, 1024, 0, stream>>>(cntG, offG, curG, rowG);
    append_g_kernel<<<(NNZ_G + 255) / 256, 256, 0, stream>>>(g_rows, g_cols, g_vals,
                                                             curG, edgeGr);
    sort_g_kernel<<<NBKT, 256, 0, stream>>>(offG, edgeGr, edgeGs, rowG);

    const int pull_grid = (N_NODES * 32 + 255) / 256;
    for (int layer = 0; layer < N_LAYERS; ++layer) {
        pull_g_kernel<<<pull_grid, 256, 0, stream>>>(rowG, edgeGs, xb, tb);
        if (layer == 0)
            pull_c_fused<1><<<pull_grid, 256, 0, stream>>>(rowC, edgeCs, cat_emb, tb,
                                                           dinv, xb, accb);
        else
            pull_c_fused<0><<<pull_grid, 256, 0, stream>>>(rowC, edgeCs, cat_emb, tb,
                                                           dinv, xb, accb);
    }

    gamma_kernel<<<(BATCH * 64 + 255) / 256, 256, 0, stream>>>(users, items, accb, out);
}

// Round 10
// 680.517 us; speedup vs baseline: 1.0725x; 1.0725x over previous
//
#include <hip/hip_runtime.h>

#define NUM_USERS 50000
#define NUM_ITEMS 50000
#define NUM_CATS  500
#define D         64
#define N_LAYERS  3
#define N_EDGES   500000
#define NNZ_G     1000000
#define NNZ_GX    2000000
#define BATCH     8192
#define N_NODES   (NUM_USERS + NUM_ITEMS)

// G-path fine buckets
#define BKT_SHIFT 4
#define BKT_W     16
#define NBKT      (N_NODES / BKT_W)   // 6250

// C-path super-buckets
#define SB_SHIFT  9
#define SB_W      512
#define NSB       ((N_NODES + SB_W - 1) / SB_W)   // 196
#define P1_K      8
#define P1_TILE   (256 * P1_K)        // 2048 nnz per WG

__device__ __forceinline__ unsigned bf16rne(float f) {
    unsigned u = __float_as_uint(f);
    return (u + 0x7FFFu + ((u >> 16) & 1u)) >> 16;
}
__device__ __forceinline__ void bf16x8_to_f8(uint4 w, float* r) {
    r[0] = __uint_as_float(w.x << 16); r[1] = __uint_as_float(w.x & 0xFFFF0000u);
    r[2] = __uint_as_float(w.y << 16); r[3] = __uint_as_float(w.y & 0xFFFF0000u);
    r[4] = __uint_as_float(w.z << 16); r[5] = __uint_as_float(w.z & 0xFFFF0000u);
    r[6] = __uint_as_float(w.w << 16); r[7] = __uint_as_float(w.w & 0xFFFF0000u);
}
__device__ __forceinline__ uint4 f8_to_bf16x8(const float* r) {
    uint4 w;
    w.x = bf16rne(r[0]) | (bf16rne(r[1]) << 16);
    w.y = bf16rne(r[2]) | (bf16rne(r[3]) << 16);
    w.z = bf16rne(r[4]) | (bf16rne(r[5]) << 16);
    w.w = bf16rne(r[6]) | (bf16rne(r[7]) << 16);
    return w;
}

// ---------- fused: degree atomics + x0 init (independent outputs) ----------
__global__ void init_deg_kernel(const float* __restrict__ ue, const float* __restrict__ ie,
                                const int* __restrict__ tu, const int* __restrict__ ti,
                                ushort* __restrict__ xb, float* __restrict__ deg) {
    int tid = blockIdx.x * blockDim.x + threadIdx.x;
    int stride = gridDim.x * blockDim.x;
    for (int e = tid; e < N_EDGES; e += stride) {
        unsafeAtomicAdd(deg + tu[e], 1.0f);
        unsafeAtomicAdd(deg + NUM_USERS + ti[e], 1.0f);
    }
    const int half = NUM_USERS * D / 4;
    for (int i4 = tid; i4 < N_NODES * D / 4; i4 += stride) {
        float4 v = (i4 < half) ? ((const float4*)ue)[i4] : ((const float4*)ie)[i4 - half];
        uint2 p;
        p.x = bf16rne(v.x) | (bf16rne(v.y) << 16);
        p.y = bf16rne(v.z) | (bf16rne(v.w) << 16);
        ((uint2*)xb)[i4] = p;
    }
}

__global__ void dinv_kernel(float* __restrict__ deg) {
    int n = blockIdx.x * blockDim.x + threadIdx.x;
    if (n < N_NODES) deg[n] = 1.0f / (deg[n] + 1e-9f);
}

// ---------- C: super-bucket histogram ----------
__global__ void histsb_c_kernel(const int* __restrict__ gx_rows,
                                const int* __restrict__ tu, const int* __restrict__ ti,
                                int* __restrict__ cnt) {
    __shared__ int h[NSB];
    for (int i = threadIdx.x; i < NSB; i += blockDim.x) h[i] = 0;
    __syncthreads();
    int stride = gridDim.x * blockDim.x;
    for (int j = blockIdx.x * blockDim.x + threadIdx.x; j < NNZ_GX; j += stride) {
        int r = gx_rows[j];
        atomicAdd(h + (tu[r] >> SB_SHIFT), 1);
        atomicAdd(h + ((NUM_USERS + ti[r]) >> SB_SHIFT), 1);
    }
    __syncthreads();
    for (int i = threadIdx.x; i < NSB; i += blockDim.x)
        if (h[i]) atomicAdd(cnt + i, h[i]);
}

// ---------- C: tiny scan ----------
__global__ void scansb_kernel(const int* __restrict__ cnt, int* __restrict__ off,
                              int* __restrict__ cur, int* __restrict__ row_sentinel) {
    if (threadIdx.x == 0) {
        int run = 0;
        for (int i = 0; i < NSB; ++i) { off[i] = run; cur[i] = run; run += cnt[i]; }
        off[NSB] = run;
        row_sentinel[0] = run;
    }
}

// ---------- C phase 1: WG multisplit append (SoA recs) ----------
__global__ void __launch_bounds__(256) p1c_kernel(
        const int* __restrict__ gx_rows, const int* __restrict__ gx_cols,
        const float* __restrict__ gx_vals,
        const int* __restrict__ tu, const int* __restrict__ ti,
        const int* __restrict__ i2c,
        int* __restrict__ sbcur, int2* __restrict__ out) {
    __shared__ int2 recs[2 * P1_TILE];            // 32 KB
    __shared__ int h[NSB], base[NSB], cur[NSB];
    int t = threadIdx.x;
    for (int i = t; i < NSB; i += 256) { h[i] = 0; cur[i] = 0; }
    __syncthreads();
    int tb = blockIdx.x * P1_TILE;
    #pragma unroll
    for (int k = 0; k < P1_K; ++k) {
        int l = t + k * 256;
        int j = tb + l;
        if (j < NNZ_GX) {
            int r = gx_rows[j], c = gx_cols[j];
            unsigned vb = bf16rne(gx_vals[j]);
            int tur = tu[r], tir = ti[r], tuc = tu[c], tic = ti[c];
            int cat = i2c[tic];
            int ylo = (int)(vb << 16) | (cat << 1);
            unsigned dstu = (unsigned)tur;           int srcu = tuc;
            unsigned dsti = (unsigned)(NUM_USERS + tir); int srci = NUM_USERS + tic;
            recs[l] = make_int2((int)((dstu << 15) | (unsigned)(srcu & 0x7FFF)),
                                ylo | (((srcu >> 15) & 3) << 10));
            recs[P1_TILE + l] = make_int2((int)((dsti << 15) | (unsigned)(srci & 0x7FFF)),
                                          ylo | (((srci >> 15) & 3) << 10) | 1);
            atomicAdd(h + (int)(dstu >> SB_SHIFT), 1);
            atomicAdd(h + (int)(dsti >> SB_SHIFT), 1);
        }
    }
    __syncthreads();
    if (t < NSB) base[t] = atomicAdd(sbcur + t, h[t]);
    __syncthreads();
    int rem = NNZ_GX - tb;
    int nv = rem < P1_TILE ? rem : P1_TILE;
    for (int s = t; s < nv; s += 256) {
        int2 rec = recs[s];
        int bkt = (int)(((unsigned)rec.x) >> 24);
        int p = base[bkt] + atomicAdd(cur + bkt, 1);
        out[p] = rec;
        rec = recs[P1_TILE + s];
        bkt = (int)(((unsigned)rec.x) >> 24);
        p = base[bkt] + atomicAdd(cur + bkt, 1);
        out[p] = rec;
    }
}

// ---------- C phase 2: per-super-bucket node sort, emits rowC (R8 version) ----------
__global__ void __launch_bounds__(512) p2c_kernel(
        const int* __restrict__ sboff, const int2* __restrict__ raw,
        int2* __restrict__ sorted, int* __restrict__ rowC) {
    int b = blockIdx.x;
    int beg = sboff[b], end = sboff[b + 1];
    __shared__ int h[SB_W], cur[SB_W];
    int t = threadIdx.x;
    h[t] = 0;
    __syncthreads();
    for (int i = beg + t; i < end; i += 512)
        atomicAdd(h + (int)((((unsigned)raw[i].x) >> 15) & (SB_W - 1)), 1);
    __syncthreads();
    int cnt = h[t];
    for (int o = 1; o < SB_W; o <<= 1) {
        int tmp = (t >= o) ? h[t - o] : 0;
        __syncthreads();
        h[t] += tmp;
        __syncthreads();
    }
    int excl = h[t] - cnt;
    cur[t] = beg + excl;
    int node = b * SB_W + t;
    if (node < N_NODES) rowC[node] = beg + excl;
    __syncthreads();
    for (int i = beg + t; i < end; i += 512) {
        int2 e = raw[i];
        unsigned rx = (unsigned)e.x;
        int dl = (int)((rx >> 15) & (SB_W - 1));
        int src = (int)(rx & 0x7FFF) | (((e.y >> 10) & 3) << 15);
        int p = atomicAdd(cur + dl, 1);
        sorted[p] = make_int2((src << 10) | (e.y & 0x3FF), e.y & 0xFFFF0000);
    }
}

// ---------- G path (R8 version) ----------
__global__ void histg_kernel(const int* __restrict__ g_rows, int* __restrict__ cnt) {
    __shared__ int h[NBKT];
    for (int i = threadIdx.x; i < NBKT; i += blockDim.x) h[i] = 0;
    __syncthreads();
    int stride = gridDim.x * blockDim.x;
    for (int e = blockIdx.x * blockDim.x + threadIdx.x; e < NNZ_G; e += stride)
        atomicAdd(h + (g_rows[e] >> BKT_SHIFT), 1);
    __syncthreads();
    for (int i = threadIdx.x; i < NBKT; i += blockDim.x)
        if (h[i]) atomicAdd(cnt + i, h[i]);
}

__global__ void scang_kernel(const int* __restrict__ cnt, int* __restrict__ off,
                             int* __restrict__ cur, int* __restrict__ row) {
    __shared__ int sums[1024];
    const int T = 1024;
    const int strip = (NBKT + T - 1) / T;
    int t = threadIdx.x;
    int beg = t * strip;
    int end = beg + strip; if (end > NBKT) end = NBKT;
    int s = 0;
    for (int i = beg; i < end; ++i) s += cnt[i];
    sums[t] = s;
    __syncthreads();
    if (t == 0) {
        int run = 0;
        for (int i = 0; i < T; ++i) { int v = sums[i]; sums[i] = run; run += v; }
        off[NBKT] = run;
        row[N_NODES] = run;
    }
    __syncthreads();
    int run = sums[t];
    for (int i = beg; i < end; ++i) { off[i] = run; cur[i] = run; run += cnt[i]; }
}

__global__ void append_g_kernel(const int* __restrict__ g_rows, const int* __restrict__ g_cols,
                                const float* __restrict__ g_vals,
                                int* __restrict__ cur, int2* __restrict__ edges) {
    int e = blockIdx.x * blockDim.x + threadIdx.x;
    if (e >= NNZ_G) return;
    int dst = g_rows[e];
    int p = atomicAdd(cur + (dst >> BKT_SHIFT), 1);
    edges[p] = make_int2(((dst & (BKT_W - 1)) << 17) | g_cols[e], __float_as_int(g_vals[e]));
}

__global__ void sort_g_kernel(const int* __restrict__ off, const int2* __restrict__ raw,
                              int2* __restrict__ sorted, int* __restrict__ rowG) {
    int b = blockIdx.x;
    int base = off[b], end = off[b + 1];
    __shared__ int hist[BKT_W], cur[BKT_W], scn[BKT_W];
    if (threadIdx.x < BKT_W) hist[threadIdx.x] = 0;
    __syncthreads();
    for (int i = base + threadIdx.x; i < end; i += blockDim.x)
        atomicAdd(hist + ((raw[i].x >> 17) & 15), 1);
    __syncthreads();
    if (threadIdx.x == 0) {
        int run = 0;
        for (int k = 0; k < BKT_W; ++k) { scn[k] = run; cur[k] = run; run += hist[k]; }
    }
    __syncthreads();
    if (threadIdx.x < BKT_W) rowG[b * BKT_W + threadIdx.x] = base + scn[threadIdx.x];
    for (int i = base + threadIdx.x; i < end; i += blockDim.x) {
        int2 e = raw[i];
        int dl = (e.x >> 17) & 15;
        int p = atomicAdd(cur + dl, 1);
        sorted[base + p] = make_int2((e.x & 0x1FFFF) << 6, e.y);  // src*64
    }
}

// ---------- pull SpMM (G): half-wave per node, 8 lanes/edge ----------
__global__ void pull_g_kernel(const int* __restrict__ row, const int2* __restrict__ edges,
                              const ushort* __restrict__ xb, ushort* __restrict__ tb) {
    int node = (blockIdx.x * blockDim.x + threadIdx.x) >> 5;
    int l32 = threadIdx.x & 31;
    if (node >= N_NODES) return;
    int g = l32 >> 3;
    int s = l32 & 7;
    int beg = row[node], end = row[node + 1];
    float acc[8] = {0.f, 0.f, 0.f, 0.f, 0.f, 0.f, 0.f, 0.f};
    #pragma unroll 2
    for (int i = beg + g; i < end; i += 4) {
        int2 e = edges[i];
        float v = __int_as_float(e.y);
        uint4 w = *(const uint4*)(xb + e.x + s * 8);
        float xv[8];
        bf16x8_to_f8(w, xv);
        #pragma unroll
        for (int d = 0; d < 8; ++d) acc[d] += v * xv[d];
    }
    #pragma unroll
    for (int d = 0; d < 8; ++d) {
        acc[d] += __shfl_xor(acc[d], 8, 64);
        acc[d] += __shfl_xor(acc[d], 16, 64);
    }
    if (l32 < 8) {
        uint4 p = f8_to_bf16x8(acc);
        *(uint4*)(tb + (size_t)node * D + s * 8) = p;
    }
}

// ---------- pull SpMM (C) + finalize: writes this layer's x (bf16) only ----------
template <int LAYER0>
__global__ void pull_c_fused(const int* __restrict__ row, const int2* __restrict__ edges,
                             const float* __restrict__ catbase,
                             const ushort* __restrict__ tb,
                             const float* __restrict__ dinv,
                             ushort* __restrict__ xout) {
    int node = (blockIdx.x * blockDim.x + threadIdx.x) >> 5;
    int l32 = threadIdx.x & 31;
    if (node >= N_NODES) return;
    int g = l32 >> 3;
    int s = l32 & 7;
    int beg = row[node], end = row[node + 1];
    float acc[8] = {0.f, 0.f, 0.f, 0.f, 0.f, 0.f, 0.f, 0.f};
    #pragma unroll 2
    for (int i = beg + g; i < end; i += 4) {
        int2 e = edges[i];
        float v = __int_as_float(e.y);
        int src = e.x >> 10;
        uint4 w = *(const uint4*)(tb + (size_t)src * D + s * 8);
        float xv[8];
        bf16x8_to_f8(w, xv);
        if (LAYER0) {
            int code = e.x & 1023;
            const float* cb = catbase + (code >> 1) * (2 * D) + ((code & 1) << 6) + s * 8;
            float4 c0 = *(const float4*)cb;
            float4 c1 = *(const float4*)(cb + 4);
            xv[0] += c0.x; xv[1] += c0.y; xv[2] += c0.z; xv[3] += c0.w;
            xv[4] += c1.x; xv[5] += c1.y; xv[6] += c1.z; xv[7] += c1.w;
        }
        #pragma unroll
        for (int d = 0; d < 8; ++d) acc[d] += v * xv[d];
    }
    #pragma unroll
    for (int d = 0; d < 8; ++d) {
        acc[d] += __shfl_xor(acc[d], 8, 64);
        acc[d] += __shfl_xor(acc[d], 16, 64);
    }
    if (l32 < 8) {
        float di = dinv[node];
        size_t o = (size_t)node * D + s * 8;
        uint4 tw = *(const uint4*)(tb + o);
        float tv[8];
        bf16x8_to_f8(tw, tv);
        float nx[8];
        #pragma unroll
        for (int d = 0; d < 8; ++d) nx[d] = (acc[d] * di + tv[d]) * 0.5f;
        *(uint4*)(xout + o) = f8_to_bf16x8(nx);
    }
}

// ---------- gamma: sum 3 layer buffers at sampled rows ----------
__global__ void gamma3_kernel(const int* __restrict__ users, const int* __restrict__ items,
                              const ushort* __restrict__ x1, const ushort* __restrict__ x2,
                              const ushort* __restrict__ x3, float* __restrict__ out) {
    int wave = (blockIdx.x * blockDim.x + threadIdx.x) >> 6;
    int lane = threadIdx.x & 63;
    if (wave >= BATCH) return;
    size_t ou = (size_t)users[wave] * D + lane;
    size_t oi = (size_t)(NUM_USERS + items[wave]) * D + lane;
    float su = __uint_as_float((unsigned)x1[ou] << 16)
             + __uint_as_float((unsigned)x2[ou] << 16)
             + __uint_as_float((unsigned)x3[ou] << 16);
    float si = __uint_as_float((unsigned)x1[oi] << 16)
             + __uint_as_float((unsigned)x2[oi] << 16)
             + __uint_as_float((unsigned)x3[oi] << 16);
    float p = su * si;
#pragma unroll
    for (int off = 32; off > 0; off >>= 1) p += __shfl_down(p, off, 64);
    if (lane == 0) out[wave] = p * (1.0f / 9.0f);
}

extern "C" void kernel_launch(void* const* d_in, const int* in_sizes, int n_in,
                              void* d_out, int out_size, void* d_ws, size_t ws_size,
                              hipStream_t stream) {
    const float* user_emb = (const float*)d_in[0];
    const float* item_emb = (const float*)d_in[1];
    const float* cat_emb  = (const float*)d_in[2];
    const float* g_vals   = (const float*)d_in[3];
    const float* gx_vals  = (const float*)d_in[4];
    const int* g_rows  = (const int*)d_in[5];
    const int* g_cols  = (const int*)d_in[6];
    const int* gx_rows = (const int*)d_in[7];
    const int* gx_cols = (const int*)d_in[8];
    const int* train_users = (const int*)d_in[9];
    const int* train_items = (const int*)d_in[10];
    const int* i2c   = (const int*)d_in[11];
    const int* users = (const int*)d_in[12];
    const int* items = (const int*)d_in[13];
    float* out = (float*)d_out;

    char* ws = (char*)d_ws;
    size_t off = 0;
    auto alloc = [&](size_t bytes) -> void* {
        void* p = ws + off;
        off += (bytes + 255) & ~(size_t)255;
        return p;
    };
    const size_t NBH = (size_t)N_NODES * D * sizeof(ushort);   // 12.8 MB
    ushort* x0b  = (ushort*)alloc(NBH);
    ushort* x1b  = (ushort*)alloc(NBH);
    ushort* x2b  = (ushort*)alloc(NBH);
    ushort* x3b  = (ushort*)alloc(NBH);
    ushort* tb   = (ushort*)alloc(NBH);
    float*  dinv = (float*)alloc((size_t)N_NODES * sizeof(float));
    int*  sbhC  = (int*)alloc((size_t)NSB * sizeof(int));
    int*  sboffC= (int*)alloc((size_t)(NSB + 1) * sizeof(int));
    int*  sbcurC= (int*)alloc((size_t)NSB * sizeof(int));
    int*  cntG  = (int*)alloc((size_t)NBKT * sizeof(int));
    int*  offG  = (int*)alloc((size_t)(NBKT + 1) * sizeof(int));
    int*  curG  = (int*)alloc((size_t)NBKT * sizeof(int));
    int*  rowC  = (int*)alloc((size_t)(N_NODES + 1) * sizeof(int));
    int*  rowG  = (int*)alloc((size_t)(N_NODES + 1) * sizeof(int));
    int2* edgeCr = (int2*)alloc((size_t)2 * NNZ_GX * sizeof(int2));
    int2* edgeCs = (int2*)alloc((size_t)2 * NNZ_GX * sizeof(int2));
    int2* edgeGr = (int2*)alloc((size_t)NNZ_G * sizeof(int2));
    int2* edgeGs = (int2*)alloc((size_t)NNZ_G * sizeof(int2));

    hipMemsetAsync(dinv, 0, (size_t)N_NODES * sizeof(float), stream);
    hipMemsetAsync(sbhC, 0, (size_t)NSB * sizeof(int), stream);
    hipMemsetAsync(cntG, 0, (size_t)NBKT * sizeof(int), stream);

    init_deg_kernel<<<4096, 256, 0, stream>>>(user_emb, item_emb, train_users, train_items,
                                              x0b, dinv);
    dinv_kernel<<<(N_NODES + 255) / 256, 256, 0, stream>>>(dinv);

    // C build
    histsb_c_kernel<<<256, 256, 0, stream>>>(gx_rows, train_users, train_items, sbhC);
    scansb_kernel<<<1, 64, 0, stream>>>(sbhC, sboffC, sbcurC, rowC + N_NODES);
    p1c_kernel<<<(NNZ_GX + P1_TILE - 1) / P1_TILE, 256, 0, stream>>>(
        gx_rows, gx_cols, gx_vals, train_users, train_items, i2c, sbcurC, edgeCr);
    p2c_kernel<<<NSB, 512, 0, stream>>>(sboffC, edgeCr, edgeCs, rowC);

    // G build
    histg_kernel<<<256, 256, 0, stream>>>(g_rows, cntG);
    scang_kernel<<<1, 1024, 0, stream>>>(cntG, offG, curG, rowG);
    append_g_kernel<<<(NNZ_G + 255) / 256, 256, 0, stream>>>(g_rows, g_cols, g_vals,
                                                             curG, edgeGr);
    sort_g_kernel<<<NBKT, 256, 0, stream>>>(offG, edgeGr, edgeGs, rowG);

    const int pull_grid = (N_NODES * 32 + 255) / 256;
    ushort* xin[4] = {x0b, x1b, x2b, x3b};
    for (int layer = 0; layer < N_LAYERS; ++layer) {
        pull_g_kernel<<<pull_grid, 256, 0, stream>>>(rowG, edgeGs, xin[layer], tb);
        if (layer == 0)
            pull_c_fused<1><<<pull_grid, 256, 0, stream>>>(rowC, edgeCs, cat_emb, tb,
                                                           dinv, xin[layer + 1]);
        else
            pull_c_fused<0><<<pull_grid, 256, 0, stream>>>(rowC, edgeCs, cat_emb, tb,
                                                           dinv, xin[layer + 1]);
    }

    gamma3_kernel<<<(BATCH * 64 + 255) / 256, 256, 0, stream>>>(users, items,
                                                                x1b, x2b, x3b, out);
}